// Round 2
// baseline (723.325 us; speedup 1.0000x reference)
//
#include <hip/hip_runtime.h>
#include <math.h>

static constexpr int D = 64;

// Filtered float atomic max. `cur` is a (possibly stale) pre-read of *p.
// out values only grow monotonically (init -inf, then maxes), so a stale
// cur is <= true value -> skipping when v <= cur is always safe.
// Bit trick: positive floats order as signed ints (atomicMax),
// negative floats order reversed as unsigned (atomicMin). Mixed cases
// converge correctly because sign bit dominates both orderings.
__device__ __forceinline__ void atomic_max_float(float* p, float v, float cur) {
  if (!(v > cur)) return;
  if (v >= 0.0f)
    atomicMax(reinterpret_cast<int*>(p), __float_as_int(v));
  else
    atomicMin(reinterpret_cast<unsigned int*>(p), __float_as_uint(v));
}

__global__ void k_init_neginf(float4* __restrict__ out, int n4) {
  int i = blockIdx.x * blockDim.x + threadIdx.x;
  if (i < n4) {
    float4 v;
    v.x = v.y = v.z = v.w = -INFINITY;
    out[i] = v;
  }
}

// y[t][n][o] = b[t][o] + sum_k x[n][k] * W[t][k][o], for t in {0,1}
// One wave per node; lane = output channel o. x-row broadcast via shfl.
__global__ __launch_bounds__(256) void k_precompute(
    const float* __restrict__ x, const float* __restrict__ W,
    const float* __restrict__ b, float* __restrict__ y, int nNodes) {
  __shared__ float Wl[2 * D * D];   // 32 KB
  __shared__ float bl[2 * D];
  for (int i = threadIdx.x; i < 2 * D * D; i += 256) Wl[i] = W[i];
  for (int i = threadIdx.x; i < 2 * D; i += 256) bl[i] = b[i];
  __syncthreads();
  const int wave = threadIdx.x >> 6;
  const int lane = threadIdx.x & 63;
  for (int n = blockIdx.x * 4 + wave; n < nNodes; n += gridDim.x * 4) {
    const float xk = x[(size_t)n * D + lane];
    float a0 = bl[lane];
    float a1 = bl[D + lane];
#pragma unroll
    for (int k = 0; k < D; ++k) {
      const float xv = __shfl(xk, k, 64);
      a0 = fmaf(xv, Wl[k * D + lane], a0);          // stride-1 across lanes: 2-way alias, free
      a1 = fmaf(xv, Wl[D * D + k * D + lane], a1);
    }
    y[(size_t)n * D + lane] = a0;
    y[(size_t)(nNodes + n) * D + lane] = a1;
  }
}

// 16 threads per edge, each handles a float4 of the 64-wide row.
__global__ void k_scatter(const int* __restrict__ ei, const int* __restrict__ ea,
                          const float* __restrict__ y, float* __restrict__ out,
                          int nEdges, int nNodes) {
  const long long tid = (long long)blockIdx.x * blockDim.x + threadIdx.x;
  const int e = (int)(tid >> 4);
  if (e >= nEdges) return;
  const int g = (int)(tid & 15);
  const int src = ei[e];
  const int dst = ei[nEdges + e];
  const int t = ea[e];
  const float4 v = *reinterpret_cast<const float4*>(
      y + ((size_t)t * nNodes + src) * D + g * 4);
  float* op = out + (size_t)dst * D + g * 4;
  // Racy filter read -- safe (see atomic_max_float comment).
  const float4 cur = *reinterpret_cast<const float4*>(op);
  atomic_max_float(op + 0, v.x, cur.x);
  atomic_max_float(op + 1, v.y, cur.y);
  atomic_max_float(op + 2, v.z, cur.z);
  atomic_max_float(op + 3, v.w, cur.w);
}

__global__ void k_fixup(float4* __restrict__ out, int n4) {
  int i = blockIdx.x * blockDim.x + threadIdx.x;
  if (i < n4) {
    float4 v = out[i];
    if (v.x == -INFINITY) v.x = 0.0f;
    if (v.y == -INFINITY) v.y = 0.0f;
    if (v.z == -INFINITY) v.z = 0.0f;
    if (v.w == -INFINITY) v.w = 0.0f;
    out[i] = v;
  }
}

// Fallback if d_ws is too small: compute message per edge on the fly.
__global__ __launch_bounds__(256) void k_edge_direct(
    const float* __restrict__ x, const float* __restrict__ W,
    const float* __restrict__ b, const int* __restrict__ ei,
    const int* __restrict__ ea, float* __restrict__ out, int nEdges) {
  __shared__ float Wl[2 * D * D];
  __shared__ float bl[2 * D];
  for (int i = threadIdx.x; i < 2 * D * D; i += 256) Wl[i] = W[i];
  for (int i = threadIdx.x; i < 2 * D; i += 256) bl[i] = b[i];
  __syncthreads();
  const int wave = threadIdx.x >> 6;
  const int lane = threadIdx.x & 63;
  for (int e = blockIdx.x * 4 + wave; e < nEdges; e += gridDim.x * 4) {
    const int src = ei[e];
    const int dst = ei[nEdges + e];
    const int t = ea[e];
    const float xk = x[(size_t)src * D + lane];
    float acc = bl[t * D + lane];
    const float* Wt = &Wl[t * D * D];
#pragma unroll
    for (int k = 0; k < D; ++k)
      acc = fmaf(__shfl(xk, k, 64), Wt[k * D + lane], acc);
    float* p = out + (size_t)dst * D + lane;
    const float cur = *p;
    atomic_max_float(p, acc, cur);
  }
}

extern "C" void kernel_launch(void* const* d_in, const int* in_sizes, int n_in,
                              void* d_out, int out_size, void* d_ws, size_t ws_size,
                              hipStream_t stream) {
  const float* x = (const float*)d_in[0];
  const float* W = (const float*)d_in[1];
  const float* b = (const float*)d_in[2];
  const int* ei = (const int*)d_in[3];   // [2, E] flat: src row then dst row
  const int* ea = (const int*)d_in[4];   // [E]
  float* out = (float*)d_out;

  const int nNodes = in_sizes[0] / D;
  const int nEdges = in_sizes[4];
  const int n4 = (nNodes * D) / 4;

  k_init_neginf<<<(n4 + 255) / 256, 256, 0, stream>>>((float4*)out, n4);

  const size_t need = (size_t)2 * nNodes * D * sizeof(float);
  if (ws_size >= need) {
    float* y = (float*)d_ws;
    k_precompute<<<2048, 256, 0, stream>>>(x, W, b, y, nNodes);
    const long long total = (long long)nEdges * 16;
    k_scatter<<<(int)((total + 255) / 256), 256, 0, stream>>>(ei, ea, y, out,
                                                              nEdges, nNodes);
  } else {
    k_edge_direct<<<4096, 256, 0, stream>>>(x, W, b, ei, ea, out, nEdges);
  }

  k_fixup<<<(n4 + 255) / 256, 256, 0, stream>>>((float4*)out, n4);
}

// Round 3
// 589.962 us; speedup vs baseline: 1.2261x; 1.2261x over previous
//
#include <hip/hip_runtime.h>
#include <math.h>

static constexpr int D = 64;

// ============================ common helpers ============================

__device__ __forceinline__ void atomic_max_float(float* p, float v, float cur) {
  if (!(v > cur)) return;
  if (v >= 0.0f)
    atomicMax(reinterpret_cast<int*>(p), __float_as_int(v));
  else
    atomicMin(reinterpret_cast<unsigned int*>(p), __float_as_uint(v));
}

__global__ void k_zero_ints(int* __restrict__ p, int n) {
  int i = blockIdx.x * blockDim.x + threadIdx.x;
  if (i < n) p[i] = 0;
}

__global__ void k_init_neginf(float4* __restrict__ out, int n4) {
  int i = blockIdx.x * blockDim.x + threadIdx.x;
  if (i < n4) {
    float4 v;
    v.x = v.y = v.z = v.w = -INFINITY;
    out[i] = v;
  }
}

// y[t][n][o] = b[t][o] + sum_k x[n][k] * W[t][k][o], t in {0,1}
__global__ __launch_bounds__(256) void k_precompute(
    const float* __restrict__ x, const float* __restrict__ W,
    const float* __restrict__ b, float* __restrict__ y, int nNodes) {
  __shared__ float Wl[2 * D * D];
  __shared__ float bl[2 * D];
  for (int i = threadIdx.x; i < 2 * D * D; i += 256) Wl[i] = W[i];
  for (int i = threadIdx.x; i < 2 * D; i += 256) bl[i] = b[i];
  __syncthreads();
  const int wave = threadIdx.x >> 6;
  const int lane = threadIdx.x & 63;
  for (int n = blockIdx.x * 4 + wave; n < nNodes; n += gridDim.x * 4) {
    const float xk = x[(size_t)n * D + lane];
    float a0 = bl[lane];
    float a1 = bl[D + lane];
#pragma unroll
    for (int k = 0; k < D; ++k) {
      const float xv = __shfl(xk, k, 64);
      a0 = fmaf(xv, Wl[k * D + lane], a0);
      a1 = fmaf(xv, Wl[D * D + k * D + lane], a1);
    }
    y[(size_t)n * D + lane] = a0;
    y[(size_t)(nNodes + n) * D + lane] = a1;
  }
}

// ============================ CSR build ============================

__global__ void k_hist(const int* __restrict__ dst, int* __restrict__ counts,
                       int nE) {
  int i = blockIdx.x * blockDim.x + threadIdx.x;
  if (i < nE) atomicAdd(&counts[dst[i]], 1);
}

// Single-block exclusive scan; counts may alias cursors (read-before-write).
__global__ __launch_bounds__(1024) void k_scan(const int* __restrict__ counts,
                                               int* __restrict__ offs,
                                               int* __restrict__ cursors,
                                               int nN) {
  __shared__ int part[1024];
  const int t = threadIdx.x;
  const int chunk = (nN + 1023) / 1024;
  const int beg = t * chunk;
  const int end = min(beg + chunk, nN);
  int s = 0;
  for (int i = beg; i < end; ++i) s += counts[i];
  part[t] = s;
  __syncthreads();
  for (int d = 1; d < 1024; d <<= 1) {
    int o = (t >= d) ? part[t - d] : 0;
    __syncthreads();
    part[t] += o;
    __syncthreads();
  }
  int base = part[t] - s;  // exclusive prefix of this chunk
  for (int i = beg; i < end; ++i) {
    const int c = counts[i];   // read BEFORE cursors[i] store (may alias)
    offs[i] = base;
    cursors[i] = base;
    base += c;
  }
  if (t == 1023) offs[nN] = part[1023];
}

__global__ void k_bucket(const int* __restrict__ src, const int* __restrict__ dst,
                         const int* __restrict__ ea, int* __restrict__ cursors,
                         unsigned* __restrict__ buckets, int nE) {
  int i = blockIdx.x * blockDim.x + threadIdx.x;
  if (i < nE) {
    int pos = atomicAdd(&cursors[dst[i]], 1);
    buckets[pos] = (unsigned)src[i] | ((unsigned)ea[i] << 31);
  }
}

// One wave per dst node: lane = channel, register max-reduce, no atomics.
__global__ __launch_bounds__(256) void k_reduce(
    const int* __restrict__ offs, const unsigned* __restrict__ buckets,
    const float* __restrict__ y, float* __restrict__ out, int nN) {
  const int wave = threadIdx.x >> 6;
  const int lane = threadIdx.x & 63;
  for (int nd = blockIdx.x * 4 + wave; nd < nN; nd += gridDim.x * 4) {
    const int beg = offs[nd];
    const int end = offs[nd + 1];
    float acc = -INFINITY;
    int j = beg;
    for (; j + 1 < end; j += 2) {
      const unsigned p0 = buckets[j];
      const unsigned p1 = buckets[j + 1];
      const float v0 = y[((size_t)(p0 >> 31) * nN + (p0 & 0x7fffffffu)) * D + lane];
      const float v1 = y[((size_t)(p1 >> 31) * nN + (p1 & 0x7fffffffu)) * D + lane];
      acc = fmaxf(acc, fmaxf(v0, v1));
    }
    if (j < end) {
      const unsigned p0 = buckets[j];
      acc = fmaxf(acc, y[((size_t)(p0 >> 31) * nN + (p0 & 0x7fffffffu)) * D + lane]);
    }
    out[(size_t)nd * D + lane] = (acc == -INFINITY) ? 0.0f : acc;
  }
}

// ============================ fallback kernels ============================

__global__ void k_scatter(const int* __restrict__ ei, const int* __restrict__ ea,
                          const float* __restrict__ y, float* __restrict__ out,
                          int nEdges, int nNodes) {
  const long long tid = (long long)blockIdx.x * blockDim.x + threadIdx.x;
  const int e = (int)(tid >> 4);
  if (e >= nEdges) return;
  const int g = (int)(tid & 15);
  const int src = ei[e];
  const int dst = ei[nEdges + e];
  const int t = ea[e];
  const float4 v = *reinterpret_cast<const float4*>(
      y + ((size_t)t * nNodes + src) * D + g * 4);
  float* op = out + (size_t)dst * D + g * 4;
  const float4 cur = *reinterpret_cast<const float4*>(op);
  atomic_max_float(op + 0, v.x, cur.x);
  atomic_max_float(op + 1, v.y, cur.y);
  atomic_max_float(op + 2, v.z, cur.z);
  atomic_max_float(op + 3, v.w, cur.w);
}

__global__ void k_fixup(float4* __restrict__ out, int n4) {
  int i = blockIdx.x * blockDim.x + threadIdx.x;
  if (i < n4) {
    float4 v = out[i];
    if (v.x == -INFINITY) v.x = 0.0f;
    if (v.y == -INFINITY) v.y = 0.0f;
    if (v.z == -INFINITY) v.z = 0.0f;
    if (v.w == -INFINITY) v.w = 0.0f;
    out[i] = v;
  }
}

__global__ __launch_bounds__(256) void k_edge_direct(
    const float* __restrict__ x, const float* __restrict__ W,
    const float* __restrict__ b, const int* __restrict__ ei,
    const int* __restrict__ ea, float* __restrict__ out, int nEdges) {
  __shared__ float Wl[2 * D * D];
  __shared__ float bl[2 * D];
  for (int i = threadIdx.x; i < 2 * D * D; i += 256) Wl[i] = W[i];
  for (int i = threadIdx.x; i < 2 * D; i += 256) bl[i] = b[i];
  __syncthreads();
  const int wave = threadIdx.x >> 6;
  const int lane = threadIdx.x & 63;
  for (int e = blockIdx.x * 4 + wave; e < nEdges; e += gridDim.x * 4) {
    const int src = ei[e];
    const int dst = ei[nEdges + e];
    const int t = ea[e];
    const float xk = x[(size_t)src * D + lane];
    float acc = bl[t * D + lane];
    const float* Wt = &Wl[t * D * D];
#pragma unroll
    for (int k = 0; k < D; ++k)
      acc = fmaf(__shfl(xk, k, 64), Wt[k * D + lane], acc);
    float* p = out + (size_t)dst * D + lane;
    const float cur = *p;
    atomic_max_float(p, acc, cur);
  }
}

// ============================ launcher ============================

extern "C" void kernel_launch(void* const* d_in, const int* in_sizes, int n_in,
                              void* d_out, int out_size, void* d_ws, size_t ws_size,
                              hipStream_t stream) {
  const float* x = (const float*)d_in[0];
  const float* W = (const float*)d_in[1];
  const float* b = (const float*)d_in[2];
  const int* ei = (const int*)d_in[3];   // [2, E]: src row then dst row
  const int* ea = (const int*)d_in[4];   // [E]
  float* out = (float*)d_out;

  const int nNodes = in_sizes[0] / D;
  const int nEdges = in_sizes[4];
  const int n4 = (nNodes * D) / 4;

  const size_t yB = (size_t)2 * nNodes * D * sizeof(float);
  auto rup = [](size_t v) { return (v + 255) & ~(size_t)255; };
  const size_t offY = 0;
  const size_t offOffs = rup(offY + yB);
  const size_t offCur = rup(offOffs + (size_t)(nNodes + 1) * sizeof(int));
  const size_t offBuck = rup(offCur + (size_t)nNodes * sizeof(int));
  const size_t needCSR = offBuck + (size_t)nEdges * sizeof(unsigned);

  if (ws_size >= needCSR) {
    char* ws = (char*)d_ws;
    float* y = (float*)(ws + offY);
    int* offs = (int*)(ws + offOffs);
    int* cursors = (int*)(ws + offCur);
    unsigned* buckets = (unsigned*)(ws + offBuck);
    int* counts = cursors;  // aliased; k_scan reads-before-writes per index

    const int* srcRow = ei;
    const int* dstRow = ei + nEdges;

    k_zero_ints<<<(nNodes + 255) / 256, 256, 0, stream>>>(counts, nNodes);
    k_hist<<<(nEdges + 255) / 256, 256, 0, stream>>>(dstRow, counts, nEdges);
    k_scan<<<1, 1024, 0, stream>>>(counts, offs, cursors, nNodes);
    k_bucket<<<(nEdges + 255) / 256, 256, 0, stream>>>(srcRow, dstRow, ea,
                                                       cursors, buckets, nEdges);
    k_precompute<<<2048, 256, 0, stream>>>(x, W, b, y, nNodes);
    k_reduce<<<(nNodes + 3) / 4, 256, 0, stream>>>(offs, buckets, y, out, nNodes);
  } else if (ws_size >= yB) {
    float* y = (float*)d_ws;
    k_init_neginf<<<(n4 + 255) / 256, 256, 0, stream>>>((float4*)out, n4);
    k_precompute<<<2048, 256, 0, stream>>>(x, W, b, y, nNodes);
    const long long total = (long long)nEdges * 16;
    k_scatter<<<(int)((total + 255) / 256), 256, 0, stream>>>(ei, ea, y, out,
                                                              nEdges, nNodes);
    k_fixup<<<(n4 + 255) / 256, 256, 0, stream>>>((float4*)out, n4);
  } else {
    k_init_neginf<<<(n4 + 255) / 256, 256, 0, stream>>>((float4*)out, n4);
    k_edge_direct<<<4096, 256, 0, stream>>>(x, W, b, ei, ea, out, nEdges);
    k_fixup<<<(n4 + 255) / 256, 256, 0, stream>>>((float4*)out, n4);
  }
}

// Round 4
// 362.216 us; speedup vs baseline: 1.9969x; 1.6288x over previous
//
#include <hip/hip_runtime.h>
#include <math.h>

static constexpr int D = 64;
static constexpr int SCAN_BLOCKS = 256;

// ============================ common helpers ============================

__device__ __forceinline__ void atomic_max_float(float* p, float v, float cur) {
  if (!(v > cur)) return;
  if (v >= 0.0f)
    atomicMax(reinterpret_cast<int*>(p), __float_as_int(v));
  else
    atomicMin(reinterpret_cast<unsigned int*>(p), __float_as_uint(v));
}

__global__ void k_init_neginf(float4* __restrict__ out, int n4) {
  int i = blockIdx.x * blockDim.x + threadIdx.x;
  if (i < n4) {
    float4 v;
    v.x = v.y = v.z = v.w = -INFINITY;
    out[i] = v;
  }
}

// y[t][n][o] = b[t][o] + sum_k x[n][k] * W[t][k][o], t in {0,1}
__global__ __launch_bounds__(256) void k_precompute(
    const float* __restrict__ x, const float* __restrict__ W,
    const float* __restrict__ b, float* __restrict__ y, int nNodes) {
  __shared__ float Wl[2 * D * D];
  __shared__ float bl[2 * D];
  for (int i = threadIdx.x; i < 2 * D * D; i += 256) Wl[i] = W[i];
  for (int i = threadIdx.x; i < 2 * D; i += 256) bl[i] = b[i];
  __syncthreads();
  const int wave = threadIdx.x >> 6;
  const int lane = threadIdx.x & 63;
  for (int n = blockIdx.x * 4 + wave; n < nNodes; n += gridDim.x * 4) {
    const float xk = x[(size_t)n * D + lane];
    float a0 = bl[lane];
    float a1 = bl[D + lane];
#pragma unroll
    for (int k = 0; k < D; ++k) {
      const float xv = __shfl(xk, k, 64);
      a0 = fmaf(xv, Wl[k * D + lane], a0);
      a1 = fmaf(xv, Wl[D * D + k * D + lane], a1);
    }
    y[(size_t)n * D + lane] = a0;
    y[(size_t)(nNodes + n) * D + lane] = a1;
  }
}

// ============================ CSR build ============================

__global__ void k_hist(const int* __restrict__ dst, int* __restrict__ counts,
                       int nE) {
  int i = blockIdx.x * blockDim.x + threadIdx.x;
  if (i < nE) atomicAdd(&counts[dst[i]], 1);
}

// Phase A: coalesced per-segment sums -> blockSums[gridDim.x].
__global__ __launch_bounds__(256) void k_scan_partial(
    const int* __restrict__ counts, int* __restrict__ blockSums, int nN) {
  __shared__ int red[256];
  const int t = threadIdx.x;
  const int seg = (nN + gridDim.x - 1) / gridDim.x;
  const int beg = blockIdx.x * seg;
  const int end = min(beg + seg, nN);
  int s = 0;
  for (int i = beg + t; i < end; i += 256) s += counts[i];
  red[t] = s;
  __syncthreads();
  for (int d = 128; d > 0; d >>= 1) {
    if (t < d) red[t] += red[t + d];
    __syncthreads();
  }
  if (t == 0) blockSums[blockIdx.x] = red[0];
}

// Phase B: single small block -- exclusive scan of blockSums; offs[nN]=total.
__global__ __launch_bounds__(256) void k_scan_block(
    int* __restrict__ blockSums, int* __restrict__ offs, int nN, int nBlocks) {
  __shared__ int sh[256];
  const int t = threadIdx.x;
  const int v = (t < nBlocks) ? blockSums[t] : 0;
  sh[t] = v;
  __syncthreads();
  for (int d = 1; d < 256; d <<= 1) {  // Hillis-Steele inclusive, race-free
    const int o = (t >= d) ? sh[t - d] : 0;
    __syncthreads();
    sh[t] += o;
    __syncthreads();
  }
  if (t < nBlocks) blockSums[t] = sh[t] - v;  // exclusive block prefix
  if (t == 255) offs[nN] = sh[255];           // total == nE
}

// Phase C: per-segment tile-wise scan; carry kept in a per-thread register
// (every thread computes the same carry -> no shared-variable race).
__global__ __launch_bounds__(256) void k_scan_write(
    const int* __restrict__ counts, const int* __restrict__ blockSums,
    int* __restrict__ offs, int* __restrict__ cursors, int nN) {
  __shared__ int sh[256];
  const int t = threadIdx.x;
  const int seg = (nN + gridDim.x - 1) / gridDim.x;
  const int beg = blockIdx.x * seg;
  const int end = min(beg + seg, nN);
  int carry = blockSums[blockIdx.x];
  for (int base = beg; base < end; base += 256) {
    const int i = base + t;
    const int v = (i < end) ? counts[i] : 0;
    sh[t] = v;
    __syncthreads();
    for (int d = 1; d < 256; d <<= 1) {  // inclusive scan, double-sync
      const int o = (t >= d) ? sh[t - d] : 0;
      __syncthreads();
      sh[t] += o;
      __syncthreads();
    }
    const int excl = carry + sh[t] - v;
    if (i < end) {
      offs[i] = excl;
      cursors[i] = excl;
    }
    carry += sh[255];   // tile total, identical in all threads
    __syncthreads();    // protect sh before next tile overwrites it
  }
}

__global__ void k_bucket(const int* __restrict__ src, const int* __restrict__ dst,
                         const int* __restrict__ ea, int* __restrict__ cursors,
                         unsigned* __restrict__ buckets, int nE) {
  int i = blockIdx.x * blockDim.x + threadIdx.x;
  if (i < nE) {
    int pos = atomicAdd(&cursors[dst[i]], 1);
    buckets[pos] = (unsigned)src[i] | ((unsigned)ea[i] << 31);
  }
}

// One wave per dst node: lane = channel, register max-reduce, no atomics.
// 4-wide unroll: 4 independent gathers in flight (latency hiding).
__global__ __launch_bounds__(256) void k_reduce(
    const int* __restrict__ offs, const unsigned* __restrict__ buckets,
    const float* __restrict__ y, float* __restrict__ out, int nN) {
  const int wave = threadIdx.x >> 6;
  const int lane = threadIdx.x & 63;
  for (int nd = blockIdx.x * 4 + wave; nd < nN; nd += gridDim.x * 4) {
    const int beg = offs[nd];
    const int end = offs[nd + 1];
    float acc = -INFINITY;
    int j = beg;
    for (; j + 3 < end; j += 4) {
      const unsigned p0 = buckets[j];
      const unsigned p1 = buckets[j + 1];
      const unsigned p2 = buckets[j + 2];
      const unsigned p3 = buckets[j + 3];
      const float v0 = y[((size_t)(p0 >> 31) * nN + (p0 & 0x7fffffffu)) * D + lane];
      const float v1 = y[((size_t)(p1 >> 31) * nN + (p1 & 0x7fffffffu)) * D + lane];
      const float v2 = y[((size_t)(p2 >> 31) * nN + (p2 & 0x7fffffffu)) * D + lane];
      const float v3 = y[((size_t)(p3 >> 31) * nN + (p3 & 0x7fffffffu)) * D + lane];
      acc = fmaxf(acc, fmaxf(fmaxf(v0, v1), fmaxf(v2, v3)));
    }
    for (; j < end; ++j) {
      const unsigned p0 = buckets[j];
      acc = fmaxf(acc, y[((size_t)(p0 >> 31) * nN + (p0 & 0x7fffffffu)) * D + lane]);
    }
    out[(size_t)nd * D + lane] = (acc == -INFINITY) ? 0.0f : acc;
  }
}

// ============================ fallback kernels ============================

__global__ void k_scatter(const int* __restrict__ ei, const int* __restrict__ ea,
                          const float* __restrict__ y, float* __restrict__ out,
                          int nEdges, int nNodes) {
  const long long tid = (long long)blockIdx.x * blockDim.x + threadIdx.x;
  const int e = (int)(tid >> 4);
  if (e >= nEdges) return;
  const int g = (int)(tid & 15);
  const int src = ei[e];
  const int dst = ei[nEdges + e];
  const int t = ea[e];
  const float4 v = *reinterpret_cast<const float4*>(
      y + ((size_t)t * nNodes + src) * D + g * 4);
  float* op = out + (size_t)dst * D + g * 4;
  const float4 cur = *reinterpret_cast<const float4*>(op);
  atomic_max_float(op + 0, v.x, cur.x);
  atomic_max_float(op + 1, v.y, cur.y);
  atomic_max_float(op + 2, v.z, cur.z);
  atomic_max_float(op + 3, v.w, cur.w);
}

__global__ void k_fixup(float4* __restrict__ out, int n4) {
  int i = blockIdx.x * blockDim.x + threadIdx.x;
  if (i < n4) {
    float4 v = out[i];
    if (v.x == -INFINITY) v.x = 0.0f;
    if (v.y == -INFINITY) v.y = 0.0f;
    if (v.z == -INFINITY) v.z = 0.0f;
    if (v.w == -INFINITY) v.w = 0.0f;
    out[i] = v;
  }
}

__global__ __launch_bounds__(256) void k_edge_direct(
    const float* __restrict__ x, const float* __restrict__ W,
    const float* __restrict__ b, const int* __restrict__ ei,
    const int* __restrict__ ea, float* __restrict__ out, int nEdges) {
  __shared__ float Wl[2 * D * D];
  __shared__ float bl[2 * D];
  for (int i = threadIdx.x; i < 2 * D * D; i += 256) Wl[i] = W[i];
  for (int i = threadIdx.x; i < 2 * D; i += 256) bl[i] = b[i];
  __syncthreads();
  const int wave = threadIdx.x >> 6;
  const int lane = threadIdx.x & 63;
  for (int e = blockIdx.x * 4 + wave; e < nEdges; e += gridDim.x * 4) {
    const int src = ei[e];
    const int dst = ei[nEdges + e];
    const int t = ea[e];
    const float xk = x[(size_t)src * D + lane];
    float acc = bl[t * D + lane];
    const float* Wt = &Wl[t * D * D];
#pragma unroll
    for (int k = 0; k < D; ++k)
      acc = fmaf(__shfl(xk, k, 64), Wt[k * D + lane], acc);
    float* p = out + (size_t)dst * D + lane;
    const float cur = *p;
    atomic_max_float(p, acc, cur);
  }
}

// ============================ launcher ============================

extern "C" void kernel_launch(void* const* d_in, const int* in_sizes, int n_in,
                              void* d_out, int out_size, void* d_ws, size_t ws_size,
                              hipStream_t stream) {
  const float* x = (const float*)d_in[0];
  const float* W = (const float*)d_in[1];
  const float* b = (const float*)d_in[2];
  const int* ei = (const int*)d_in[3];   // [2, E]: src row then dst row
  const int* ea = (const int*)d_in[4];   // [E]
  float* out = (float*)d_out;

  const int nNodes = in_sizes[0] / D;
  const int nEdges = in_sizes[4];
  const int n4 = (nNodes * D) / 4;

  // Workspace carve (256B-aligned regions).
  const size_t yB = (size_t)2 * nNodes * D * sizeof(float);
  auto rup = [](size_t v) { return (v + 255) & ~(size_t)255; };
  const size_t offY = 0;
  const size_t offCounts = rup(offY + yB);
  const size_t offOffs = rup(offCounts + (size_t)nNodes * sizeof(int));
  const size_t offCur = rup(offOffs + (size_t)(nNodes + 1) * sizeof(int));
  const size_t offBS = rup(offCur + (size_t)nNodes * sizeof(int));
  const size_t offBuck = rup(offBS + (size_t)SCAN_BLOCKS * sizeof(int));
  const size_t needCSR = offBuck + (size_t)nEdges * sizeof(unsigned);

  if (ws_size >= needCSR) {
    // ---- CSR two-pass path (no float atomics) ----
    char* ws = (char*)d_ws;
    float* y = (float*)(ws + offY);
    int* counts = (int*)(ws + offCounts);
    int* offs = (int*)(ws + offOffs);
    int* cursors = (int*)(ws + offCur);
    int* blockSums = (int*)(ws + offBS);
    unsigned* buckets = (unsigned*)(ws + offBuck);

    const int* srcRow = ei;
    const int* dstRow = ei + nEdges;

    hipMemsetAsync(counts, 0, (size_t)nNodes * sizeof(int), stream);
    k_hist<<<(nEdges + 255) / 256, 256, 0, stream>>>(dstRow, counts, nEdges);
    k_scan_partial<<<SCAN_BLOCKS, 256, 0, stream>>>(counts, blockSums, nNodes);
    k_scan_block<<<1, 256, 0, stream>>>(blockSums, offs, nNodes, SCAN_BLOCKS);
    k_scan_write<<<SCAN_BLOCKS, 256, 0, stream>>>(counts, blockSums, offs,
                                                  cursors, nNodes);
    k_bucket<<<(nEdges + 255) / 256, 256, 0, stream>>>(srcRow, dstRow, ea,
                                                       cursors, buckets, nEdges);
    k_precompute<<<2048, 256, 0, stream>>>(x, W, b, y, nNodes);
    k_reduce<<<(nNodes + 3) / 4, 256, 0, stream>>>(offs, buckets, y, out, nNodes);
  } else if (ws_size >= yB) {
    // ---- atomic fallback ----
    float* y = (float*)d_ws;
    k_init_neginf<<<(n4 + 255) / 256, 256, 0, stream>>>((float4*)out, n4);
    k_precompute<<<2048, 256, 0, stream>>>(x, W, b, y, nNodes);
    const long long total = (long long)nEdges * 16;
    k_scatter<<<(int)((total + 255) / 256), 256, 0, stream>>>(ei, ea, y, out,
                                                              nEdges, nNodes);
    k_fixup<<<(n4 + 255) / 256, 256, 0, stream>>>((float4*)out, n4);
  } else {
    k_init_neginf<<<(n4 + 255) / 256, 256, 0, stream>>>((float4*)out, n4);
    k_edge_direct<<<4096, 256, 0, stream>>>(x, W, b, ei, ea, out, nEdges);
    k_fixup<<<(n4 + 255) / 256, 256, 0, stream>>>((float4*)out, n4);
  }
}

// Round 5
// 294.409 us; speedup vs baseline: 2.4569x; 1.2303x over previous
//
#include <hip/hip_runtime.h>
#include <math.h>

static constexpr int D = 64;
static constexpr int SCAN_BLOCKS = 256;

typedef __bf16 bf16x8 __attribute__((ext_vector_type(8)));
typedef float f32x4 __attribute__((ext_vector_type(4)));

// ============================ common helpers ============================

__device__ __forceinline__ unsigned short f2bf(float f) {  // RNE
  unsigned u = __float_as_uint(f);
  return (unsigned short)((u + 0x7fffu + ((u >> 16) & 1u)) >> 16);
}
__device__ __forceinline__ float bf2f(unsigned short h) {
  return __uint_as_float((unsigned)h << 16);
}

__device__ __forceinline__ void atomic_max_float(float* p, float v, float cur) {
  if (!(v > cur)) return;
  if (v >= 0.0f)
    atomicMax(reinterpret_cast<int*>(p), __float_as_int(v));
  else
    atomicMin(reinterpret_cast<unsigned int*>(p), __float_as_uint(v));
}

__global__ void k_init_neginf(float4* __restrict__ out, int n4) {
  int i = blockIdx.x * blockDim.x + threadIdx.x;
  if (i < n4) {
    float4 v;
    v.x = v.y = v.z = v.w = -INFINITY;
    out[i] = v;
  }
}

// x fp32 -> bf16, 4 elems/thread.
__global__ __launch_bounds__(256) void k_cvt(const float4* __restrict__ x,
                                             ushort2* __restrict__ xb, int n4) {
  for (int i = blockIdx.x * blockDim.x + threadIdx.x; i < n4;
       i += gridDim.x * blockDim.x) {
    const float4 v = x[i];
    ushort2 a, b;
    a.x = f2bf(v.x); a.y = f2bf(v.y);
    b.x = f2bf(v.z); b.y = f2bf(v.w);
    xb[i * 2] = a;
    xb[i * 2 + 1] = b;
  }
}

// ============================ MFMA precompute ============================
// yb[t][n][o] = bf16( b[t][o] + sum_k x[n][k] * W[t][k][o] ), t in {0,1}
// Per wave: 16-node chunk, 8 n-tiles (2 types x 4 col-tiles), K=64 in 2 steps.
// mfma_f32_16x16x32_bf16 layouts (m89-verified D): A: row=lane&15,
// k=8*(lane>>4)+e ; B: col=lane&15, k likewise ; D: col=lane&15,
// row=4*(lane>>4)+r.
__global__ __launch_bounds__(256) void k_gemm(
    const unsigned short* __restrict__ xb, const float* __restrict__ W,
    const float* __restrict__ b, unsigned short* __restrict__ yb, int nN) {
  const int lane = threadIdx.x & 63;
  const int wid = (blockIdx.x << 2) + (threadIdx.x >> 6);
  const int nWaves = gridDim.x << 2;
  const int kgrp = (lane >> 4) << 3;  // 0,8,16,24
  const int nsub = lane & 15;

  bf16x8 Bf[8][2];
  float bias[8];
#pragma unroll
  for (int nt = 0; nt < 8; ++nt) {
    const int t = nt >> 2;
    const int n = ((nt & 3) << 4) + nsub;
#pragma unroll
    for (int ks = 0; ks < 2; ++ks) {
      bf16x8 f;
#pragma unroll
      for (int e = 0; e < 8; ++e) {
        const int k = (ks << 5) + kgrp + e;
        f[e] = (__bf16)W[t * 4096 + k * 64 + n];
      }
      Bf[nt][ks] = f;
    }
    bias[nt] = b[t * 64 + n];
  }

  const int nChunks = (nN + 15) >> 4;
  for (int c = wid; c < nChunks; c += nWaves) {
    const int base = c << 4;
    const int arow = min(base + nsub, nN - 1);
    const bf16x8 a0 =
        *reinterpret_cast<const bf16x8*>(xb + (size_t)arow * 64 + kgrp);
    const bf16x8 a1 =
        *reinterpret_cast<const bf16x8*>(xb + (size_t)arow * 64 + 32 + kgrp);
#pragma unroll
    for (int nt = 0; nt < 8; ++nt) {
      f32x4 acc = {bias[nt], bias[nt], bias[nt], bias[nt]};
      acc = __builtin_amdgcn_mfma_f32_16x16x32_bf16(a0, Bf[nt][0], acc, 0, 0, 0);
      acc = __builtin_amdgcn_mfma_f32_16x16x32_bf16(a1, Bf[nt][1], acc, 0, 0, 0);
      const int t = nt >> 2;
      const int o = ((nt & 3) << 4) + nsub;
      const int rbase = base + ((lane >> 4) << 2);
#pragma unroll
      for (int r = 0; r < 4; ++r) {
        const int node = rbase + r;
        if (node < nN) yb[((size_t)t * nN + node) * 64 + o] = f2bf(acc[r]);
      }
    }
  }
}

// ============================ CSR build ============================

__global__ void k_hist(const int* __restrict__ dst, int* __restrict__ counts,
                       int nE) {
  int i = blockIdx.x * blockDim.x + threadIdx.x;
  if (i < nE) atomicAdd(&counts[dst[i]], 1);
}

__global__ __launch_bounds__(256) void k_scan_partial(
    const int* __restrict__ counts, int* __restrict__ blockSums, int nN) {
  __shared__ int red[256];
  const int t = threadIdx.x;
  const int seg = (nN + gridDim.x - 1) / gridDim.x;
  const int beg = blockIdx.x * seg;
  const int end = min(beg + seg, nN);
  int s = 0;
  for (int i = beg + t; i < end; i += 256) s += counts[i];
  red[t] = s;
  __syncthreads();
  for (int d = 128; d > 0; d >>= 1) {
    if (t < d) red[t] += red[t + d];
    __syncthreads();
  }
  if (t == 0) blockSums[blockIdx.x] = red[0];
}

__global__ __launch_bounds__(256) void k_scan_block(
    int* __restrict__ blockSums, int* __restrict__ offs, int nN, int nBlocks) {
  __shared__ int sh[256];
  const int t = threadIdx.x;
  const int v = (t < nBlocks) ? blockSums[t] : 0;
  sh[t] = v;
  __syncthreads();
  for (int d = 1; d < 256; d <<= 1) {
    const int o = (t >= d) ? sh[t - d] : 0;
    __syncthreads();
    sh[t] += o;
    __syncthreads();
  }
  if (t < nBlocks) blockSums[t] = sh[t] - v;
  if (t == 255) offs[nN] = sh[255];
}

__global__ __launch_bounds__(256) void k_scan_write(
    const int* __restrict__ counts, const int* __restrict__ blockSums,
    int* __restrict__ offs, int* __restrict__ cursors, int nN) {
  __shared__ int sh[256];
  const int t = threadIdx.x;
  const int seg = (nN + gridDim.x - 1) / gridDim.x;
  const int beg = blockIdx.x * seg;
  const int end = min(beg + seg, nN);
  int carry = blockSums[blockIdx.x];
  for (int base = beg; base < end; base += 256) {
    const int i = base + t;
    const int v = (i < end) ? counts[i] : 0;
    sh[t] = v;
    __syncthreads();
    for (int d = 1; d < 256; d <<= 1) {
      const int o = (t >= d) ? sh[t - d] : 0;
      __syncthreads();
      sh[t] += o;
      __syncthreads();
    }
    const int excl = carry + sh[t] - v;
    if (i < end) {
      offs[i] = excl;
      cursors[i] = excl;
    }
    carry += sh[255];
    __syncthreads();
  }
}

__global__ void k_bucket(const int* __restrict__ src, const int* __restrict__ dst,
                         const int* __restrict__ ea, int* __restrict__ cursors,
                         unsigned* __restrict__ buckets, int nE) {
  int i = blockIdx.x * blockDim.x + threadIdx.x;
  if (i < nE) {
    int pos = atomicAdd(&cursors[dst[i]], 1);
    buckets[pos] = (unsigned)src[i] | ((unsigned)ea[i] << 31);
  }
}

// One wave per dst node; lane = channel. bf16 gather (128B/row), f32 max.
__global__ __launch_bounds__(256) void k_reduce(
    const int* __restrict__ offs, const unsigned* __restrict__ buckets,
    const unsigned short* __restrict__ yb, float* __restrict__ out, int nN) {
  const int wave = threadIdx.x >> 6;
  const int lane = threadIdx.x & 63;
  for (int nd = blockIdx.x * 4 + wave; nd < nN; nd += gridDim.x * 4) {
    const int beg = offs[nd];
    const int end = offs[nd + 1];
    float acc = -INFINITY;
    int j = beg;
    for (; j + 3 < end; j += 4) {
      const unsigned p0 = buckets[j];
      const unsigned p1 = buckets[j + 1];
      const unsigned p2 = buckets[j + 2];
      const unsigned p3 = buckets[j + 3];
      const float v0 = bf2f(yb[((size_t)(p0 >> 31) * nN + (p0 & 0x7fffffffu)) * D + lane]);
      const float v1 = bf2f(yb[((size_t)(p1 >> 31) * nN + (p1 & 0x7fffffffu)) * D + lane]);
      const float v2 = bf2f(yb[((size_t)(p2 >> 31) * nN + (p2 & 0x7fffffffu)) * D + lane]);
      const float v3 = bf2f(yb[((size_t)(p3 >> 31) * nN + (p3 & 0x7fffffffu)) * D + lane]);
      acc = fmaxf(acc, fmaxf(fmaxf(v0, v1), fmaxf(v2, v3)));
    }
    for (; j < end; ++j) {
      const unsigned p0 = buckets[j];
      acc = fmaxf(acc, bf2f(yb[((size_t)(p0 >> 31) * nN + (p0 & 0x7fffffffu)) * D + lane]));
    }
    out[(size_t)nd * D + lane] = (acc == -INFINITY) ? 0.0f : acc;
  }
}

// ============================ fallback kernels ============================

__global__ __launch_bounds__(256) void k_precompute(
    const float* __restrict__ x, const float* __restrict__ W,
    const float* __restrict__ b, float* __restrict__ y, int nNodes) {
  __shared__ float Wl[2 * D * D];
  __shared__ float bl[2 * D];
  for (int i = threadIdx.x; i < 2 * D * D; i += 256) Wl[i] = W[i];
  for (int i = threadIdx.x; i < 2 * D; i += 256) bl[i] = b[i];
  __syncthreads();
  const int wave = threadIdx.x >> 6;
  const int lane = threadIdx.x & 63;
  for (int n = blockIdx.x * 4 + wave; n < nNodes; n += gridDim.x * 4) {
    const float xk = x[(size_t)n * D + lane];
    float a0 = bl[lane];
    float a1 = bl[D + lane];
#pragma unroll
    for (int k = 0; k < D; ++k) {
      const float xv = __shfl(xk, k, 64);
      a0 = fmaf(xv, Wl[k * D + lane], a0);
      a1 = fmaf(xv, Wl[D * D + k * D + lane], a1);
    }
    y[(size_t)n * D + lane] = a0;
    y[(size_t)(nNodes + n) * D + lane] = a1;
  }
}

__global__ void k_scatter(const int* __restrict__ ei, const int* __restrict__ ea,
                          const float* __restrict__ y, float* __restrict__ out,
                          int nEdges, int nNodes) {
  const long long tid = (long long)blockIdx.x * blockDim.x + threadIdx.x;
  const int e = (int)(tid >> 4);
  if (e >= nEdges) return;
  const int g = (int)(tid & 15);
  const int src = ei[e];
  const int dst = ei[nEdges + e];
  const int t = ea[e];
  const float4 v = *reinterpret_cast<const float4*>(
      y + ((size_t)t * nNodes + src) * D + g * 4);
  float* op = out + (size_t)dst * D + g * 4;
  const float4 cur = *reinterpret_cast<const float4*>(op);
  atomic_max_float(op + 0, v.x, cur.x);
  atomic_max_float(op + 1, v.y, cur.y);
  atomic_max_float(op + 2, v.z, cur.z);
  atomic_max_float(op + 3, v.w, cur.w);
}

__global__ void k_fixup(float4* __restrict__ out, int n4) {
  int i = blockIdx.x * blockDim.x + threadIdx.x;
  if (i < n4) {
    float4 v = out[i];
    if (v.x == -INFINITY) v.x = 0.0f;
    if (v.y == -INFINITY) v.y = 0.0f;
    if (v.z == -INFINITY) v.z = 0.0f;
    if (v.w == -INFINITY) v.w = 0.0f;
    out[i] = v;
  }
}

__global__ __launch_bounds__(256) void k_edge_direct(
    const float* __restrict__ x, const float* __restrict__ W,
    const float* __restrict__ b, const int* __restrict__ ei,
    const int* __restrict__ ea, float* __restrict__ out, int nEdges) {
  __shared__ float Wl[2 * D * D];
  __shared__ float bl[2 * D];
  for (int i = threadIdx.x; i < 2 * D * D; i += 256) Wl[i] = W[i];
  for (int i = threadIdx.x; i < 2 * D; i += 256) bl[i] = b[i];
  __syncthreads();
  const int wave = threadIdx.x >> 6;
  const int lane = threadIdx.x & 63;
  for (int e = blockIdx.x * 4 + wave; e < nEdges; e += gridDim.x * 4) {
    const int src = ei[e];
    const int dst = ei[nEdges + e];
    const int t = ea[e];
    const float xk = x[(size_t)src * D + lane];
    float acc = bl[t * D + lane];
    const float* Wt = &Wl[t * D * D];
#pragma unroll
    for (int k = 0; k < D; ++k)
      acc = fmaf(__shfl(xk, k, 64), Wt[k * D + lane], acc);
    float* p = out + (size_t)dst * D + lane;
    const float cur = *p;
    atomic_max_float(p, acc, cur);
  }
}

// ============================ launcher ============================

extern "C" void kernel_launch(void* const* d_in, const int* in_sizes, int n_in,
                              void* d_out, int out_size, void* d_ws, size_t ws_size,
                              hipStream_t stream) {
  const float* x = (const float*)d_in[0];
  const float* W = (const float*)d_in[1];
  const float* b = (const float*)d_in[2];
  const int* ei = (const int*)d_in[3];   // [2, E]: src row then dst row
  const int* ea = (const int*)d_in[4];   // [E]
  float* out = (float*)d_out;

  const int nNodes = in_sizes[0] / D;
  const int nEdges = in_sizes[4];
  const int n4out = (nNodes * D) / 4;

  // Workspace carve (256B-aligned regions).
  auto rup = [](size_t v) { return (v + 255) & ~(size_t)255; };
  const size_t xbB = (size_t)nNodes * D * sizeof(unsigned short);
  const size_t ybB = (size_t)2 * nNodes * D * sizeof(unsigned short);
  const size_t offXb = 0;
  const size_t offYb = rup(offXb + xbB);
  const size_t offCounts = rup(offYb + ybB);
  const size_t offOffs = rup(offCounts + (size_t)nNodes * sizeof(int));
  const size_t offCur = rup(offOffs + (size_t)(nNodes + 1) * sizeof(int));
  const size_t offBS = rup(offCur + (size_t)nNodes * sizeof(int));
  const size_t offBuck = rup(offBS + (size_t)SCAN_BLOCKS * sizeof(int));
  const size_t needCSR = offBuck + (size_t)nEdges * sizeof(unsigned);
  const size_t yF32B = (size_t)2 * nNodes * D * sizeof(float);

  if (ws_size >= needCSR) {
    // ---- bf16 MFMA + CSR two-pass path ----
    char* ws = (char*)d_ws;
    unsigned short* xb = (unsigned short*)(ws + offXb);
    unsigned short* yb = (unsigned short*)(ws + offYb);
    int* counts = (int*)(ws + offCounts);
    int* offs = (int*)(ws + offOffs);
    int* cursors = (int*)(ws + offCur);
    int* blockSums = (int*)(ws + offBS);
    unsigned* buckets = (unsigned*)(ws + offBuck);

    const int* srcRow = ei;
    const int* dstRow = ei + nEdges;
    const int nX4 = (nNodes * D) / 4;

    hipMemsetAsync(counts, 0, (size_t)nNodes * sizeof(int), stream);
    k_cvt<<<2048, 256, 0, stream>>>((const float4*)x, (ushort2*)xb, nX4);
    k_hist<<<(nEdges + 255) / 256, 256, 0, stream>>>(dstRow, counts, nEdges);
    k_scan_partial<<<SCAN_BLOCKS, 256, 0, stream>>>(counts, blockSums, nNodes);
    k_scan_block<<<1, 256, 0, stream>>>(blockSums, offs, nNodes, SCAN_BLOCKS);
    k_scan_write<<<SCAN_BLOCKS, 256, 0, stream>>>(counts, blockSums, offs,
                                                  cursors, nNodes);
    k_bucket<<<(nEdges + 255) / 256, 256, 0, stream>>>(srcRow, dstRow, ea,
                                                       cursors, buckets, nEdges);
    k_gemm<<<256, 256, 0, stream>>>(xb, W, b, yb, nNodes);
    k_reduce<<<(nNodes + 3) / 4, 256, 0, stream>>>(offs, buckets, yb, out, nNodes);
  } else if (ws_size >= yF32B) {
    // ---- fp32 atomic fallback ----
    float* y = (float*)d_ws;
    k_init_neginf<<<(n4out + 255) / 256, 256, 0, stream>>>((float4*)out, n4out);
    k_precompute<<<2048, 256, 0, stream>>>(x, W, b, y, nNodes);
    const long long total = (long long)nEdges * 16;
    k_scatter<<<(int)((total + 255) / 256), 256, 0, stream>>>(ei, ea, y, out,
                                                              nEdges, nNodes);
    k_fixup<<<(n4out + 255) / 256, 256, 0, stream>>>((float4*)out, n4out);
  } else {
    k_init_neginf<<<(n4out + 255) / 256, 256, 0, stream>>>((float4*)out, n4out);
    k_edge_direct<<<4096, 256, 0, stream>>>(x, W, b, ei, ea, out, nEdges);
    k_fixup<<<(n4out + 255) / 256, 256, 0, stream>>>((float4*)out, n4out);
  }
}